// Round 16
// baseline (86.068 us; speedup 1.0000x reference)
//
#include <hip/hip_runtime.h>
#include <hip/hip_bf16.h>

// SelfAttention b=2, heads=8, D=32, n=4096 (64x64).
// Pass 1 (proj_kernel, z=Q/K/V): x -> Q bf16 [bg][n][32] (pre-scaled by
//   SCALE*log2e), K2 bf16 [bg][dgrp=d/8][key][8], V2 bf16 sigma-ordered
//   [bg][key16grp][h][d][8] (r15-proven: PV A-frags = direct cvt_pk of
//   exp2 outputs, no cross-lane ops).
// Pass 2 (attn_kernel): 32x32 MFMA flash attention, 32 q/wave, KVBLK=32,
//   no LDS in loop. r16: MANUAL SOFTWARE PIPELINE -- S[t+1] is computed
//   BEFORE exp2/PV of tile t (K prefetched depth 2, V depth 1), so the
//   MFMA pipe (S[t+1]) and VALU pipe (exp2/cvt of tile t) overlap instead
//   of serializing (r15 showed VALU 59% / MFMA 27% with ~40% dep gaps).
//   lsum on the matrix pipe via mfma(P,ones) (r15-proven, lane-local
//   normalize). Endgame LDS transpose for the Wp-projection (r13-proven).

constexpr int D = 32;
constexpr int N = 4096;
constexpr int NBG = 16;
constexpr float SCALE = 0.17677669529663687f;   // 32^-0.5
constexpr float LOG2E = 1.4426950408889634f;

using bfrag  = __attribute__((ext_vector_type(8))) short;   // 8 bf16
using s16x8  = __attribute__((ext_vector_type(8))) short;
using f32x16 = __attribute__((ext_vector_type(16))) float;
typedef unsigned short u16;
typedef unsigned int u32;

constexpr int PSTR = 34;            // endgame tile row stride in u16

__device__ __forceinline__ float fexp2(float x) { return __builtin_amdgcn_exp2f(x); }

__device__ __forceinline__ short f2bfs(float f) {
    __hip_bfloat16 h = __float2bfloat16(f);
    return (short)__builtin_bit_cast(u16, h);
}

__device__ __forceinline__ u32 cvt_pk_bf16(float lo, float hi) {
    u32 r;
    asm("v_cvt_pk_bf16_f32 %0, %1, %2" : "=v"(r) : "v"(lo), "v"(hi));
    return r;
}

// ---------------- pass 1: projections -> fragment-native bf16 scratch -----
__global__ __launch_bounds__(256) void proj_kernel(
    const float* __restrict__ x,
    const float* __restrict__ Wq, const float* __restrict__ bq,
    const float* __restrict__ Wk, const float* __restrict__ bk,
    const float* __restrict__ Wv, const float* __restrict__ bv,
    u16* __restrict__ Qb, u16* __restrict__ K2, u16* __restrict__ V2) {
    const int bg = blockIdx.y, g = bg & 7;
    const int z  = blockIdx.z;                       // 0=Q 1=K 2=V
    const int i  = blockIdx.x * 256 + threadIdx.x;   // key / pixel index

    const float* W  = (z == 0) ? Wq : (z == 1) ? Wk : Wv;
    const float* bb = (z == 0) ? bq : (z == 1) ? bk : bv;

    const float* xb = x + (size_t)bg * D * N;
    float xv[D];
#pragma unroll
    for (int d = 0; d < D; ++d) xv[d] = xb[(size_t)d * N + i];

    const float* w = W + g * D * D;
    float acc[D];
#pragma unroll
    for (int o = 0; o < D; ++o) {
        float a0 = 0.f, a1 = 0.f, a2 = 0.f, a3 = 0.f;
#pragma unroll
        for (int d = 0; d < D; d += 4) {
            a0 = fmaf(w[o * D + d    ], xv[d    ], a0);
            a1 = fmaf(w[o * D + d + 1], xv[d + 1], a1);
            a2 = fmaf(w[o * D + d + 2], xv[d + 2], a2);
            a3 = fmaf(w[o * D + d + 3], xv[d + 3], a3);
        }
        acc[o] = (a0 + a1) + (a2 + a3) + bb[g * D + o];
    }

    if (z == 0) {                                    // Q -> row [n][32]
        u16* dst = Qb + ((size_t)bg * N + i) * D;
#pragma unroll
        for (int t = 0; t < 4; ++t) {
            s16x8 v;
#pragma unroll
            for (int e = 0; e < 8; ++e) v[e] = f2bfs(acc[8 * t + e] * (SCALE * LOG2E));
            *reinterpret_cast<s16x8*>(dst + 8 * t) = v;
        }
    } else if (z == 1) {                             // K -> [dgrp][key][8]
        u16* kb2 = K2 + (size_t)bg * N * D;
#pragma unroll
        for (int t = 0; t < 4; ++t) {                // dgrp = t
            s16x8 v;
#pragma unroll
            for (int e = 0; e < 8; ++e) v[e] = f2bfs(acc[8 * t + e]);
            *reinterpret_cast<s16x8*>(kb2 + (size_t)t * N * 8 + (size_t)i * 8) = v;
        }
    } else {
        // V -> sigma-ordered [key16grp][h][d][8]:
        // key j=i&15 sits at h=(j>>2)&1, e=(j&3)+4*((j>>3)&1), matching the
        // S^T in-lane key order (row = (e&3)+8*(e>>2)+4h) -> no permswap.
        const int j  = i & 15;
        const int hh = (j >> 2) & 1;
        const int ee = (j & 3) + 4 * ((j >> 3) & 1);
        u16* vb2 = V2 + (size_t)bg * N * D + (size_t)(i >> 4) * 512 + hh * 256 + ee;
#pragma unroll
        for (int o = 0; o < D; ++o)
            vb2[o * 8] = (u16)f2bfs(acc[o]);
    }
}

// ---------------- pass 2: 32x32 MFMA flash attention, SW-pipelined --------
__global__ __launch_bounds__(256) void attn_kernel(
    const u16* __restrict__ Qb, const u16* __restrict__ K2, const u16* __restrict__ V2,
    const float* __restrict__ Wp, const float* __restrict__ bp,
    float* __restrict__ out) {
    const int s = blockIdx.x;
    const int bg = s & 15, qt = s >> 4, g = bg & 7;   // bg fastest -> XCD L2 reuse
    const int wid = threadIdx.x >> 6;
    const int lane = threadIdx.x & 63;
    const int l31 = lane & 31, h = lane >> 5;
    const int qbase = qt * 128 + wid * 32;            // 32 q rows per wave

    __shared__ u16 plds_all[4][32][PSTR];             // endgame transpose only
    u16* tile = &plds_all[wid][0][0];

    const u16* Qw = Qb + (size_t)bg * N * D;
    const u16* Kw = K2 + (size_t)bg * N * D;
    const u16* Vw = V2 + (size_t)bg * N * D;

    // Q B-fragments (col=q=l31, k-slots d=8h+e), held whole loop
    const u16* qrow = Qw + (size_t)(qbase + l31) * D + 8 * h;
    bfrag qf0 = *reinterpret_cast<const bfrag*>(qrow);
    bfrag qf1 = *reinterpret_cast<const bfrag*>(qrow + 16);

    // Wp B-fragments (col=o=l31, k-slots d=8h+e) + bias
    bfrag wf0, wf1;
    {
        const float* wrow = Wp + (size_t)(g * D + l31) * D + 8 * h;
#pragma unroll
        for (int e = 0; e < 8; ++e) { wf0[e] = f2bfs(wrow[e]); wf1[e] = f2bfs(wrow[16 + e]); }
    }
    const float bias = bp[g * D + l31];

    // ones B-fragment (bf16 1.0) for the lsum MFMA
    bfrag onesf;
#pragma unroll
    for (int e = 0; e < 8; ++e) onesf[e] = (short)0x3F80;

    const f32x16 zf16 = {};          // persistent zero accumulator seed
    f32x16 oacc  = {};
    f32x16 lsacc = {};

    // fragment-native bases: every in-loop load is 1KB contiguous per wave
    const u16* kBase   = Kw + (size_t)h * N * 8 + (size_t)l31 * 8;  // dgrp h, key l31
    const u16* kHiBase = kBase + 2 * N * 8;                         // dgrp h+2
    const u16* vBase   = Vw + h * 256 + l31 * 8;                    // h-group, d=l31

    const int NT = N / 32;

    // ---- pipeline prologue ----
    bfrag kA = *reinterpret_cast<const bfrag*>(kBase);
    bfrag kB = *reinterpret_cast<const bfrag*>(kHiBase);
    bfrag vA = *reinterpret_cast<const bfrag*>(vBase);
    bfrag vB = *reinterpret_cast<const bfrag*>(vBase + 512);

    f32x16 scur = __builtin_amdgcn_mfma_f32_32x32x16_bf16(kA, qf0, zf16, 0, 0, 0);
    scur = __builtin_amdgcn_mfma_f32_32x32x16_bf16(kB, qf1, scur, 0, 0, 0);

    kA = *reinterpret_cast<const bfrag*>(kBase + 256);      // K[1]
    kB = *reinterpret_cast<const bfrag*>(kHiBase + 256);

    for (int t = 0; t < NT - 1; ++t) {
        // 1. S for tile t+1 (kA/kB = K[t+1]) -- issued BEFORE current exp/PV
        f32x16 snext = __builtin_amdgcn_mfma_f32_32x32x16_bf16(kA, qf0, zf16, 0, 0, 0);
        snext = __builtin_amdgcn_mfma_f32_32x32x16_bf16(kB, qf1, snext, 0, 0, 0);

        // 2. prefetch K[t+2] (clamped in-range; dead value on last iter),
        //    V[t+1]
        const int tk = (t + 2 < NT) ? (t + 2) : (NT - 1);
        kA = *reinterpret_cast<const bfrag*>(kBase   + (size_t)tk * 256);
        kB = *reinterpret_cast<const bfrag*>(kHiBase + (size_t)tk * 256);
        bfrag vAn = *reinterpret_cast<const bfrag*>(vBase + (size_t)(t + 1) * 1024);
        bfrag vBn = *reinterpret_cast<const bfrag*>(vBase + (size_t)(t + 1) * 1024 + 512);

        // 3. exp2 + pack for tile t (VALU, overlaps S[t+1] on MFMA pipe)
        float p[16];
#pragma unroll
        for (int r = 0; r < 16; ++r) p[r] = fexp2(scur[r]);
        uint4 f1 = make_uint4(cvt_pk_bf16(p[0],  p[1]),  cvt_pk_bf16(p[2],  p[3]),
                              cvt_pk_bf16(p[4],  p[5]),  cvt_pk_bf16(p[6],  p[7]));
        uint4 f2 = make_uint4(cvt_pk_bf16(p[8],  p[9]),  cvt_pk_bf16(p[10], p[11]),
                              cvt_pk_bf16(p[12], p[13]), cvt_pk_bf16(p[14], p[15]));
        const bfrag pf1 = __builtin_bit_cast(bfrag, f1);
        const bfrag pf2 = __builtin_bit_cast(bfrag, f2);

        // 4. PV + lsum for tile t
        oacc  = __builtin_amdgcn_mfma_f32_32x32x16_bf16(pf1, vA,    oacc,  0, 0, 0);
        oacc  = __builtin_amdgcn_mfma_f32_32x32x16_bf16(pf2, vB,    oacc,  0, 0, 0);
        lsacc = __builtin_amdgcn_mfma_f32_32x32x16_bf16(pf1, onesf, lsacc, 0, 0, 0);
        lsacc = __builtin_amdgcn_mfma_f32_32x32x16_bf16(pf2, onesf, lsacc, 0, 0, 0);

        // 5. rotate
        scur = snext; vA = vAn; vB = vBn;
    }

    // ---- pipeline epilogue: final tile ----
    {
        float p[16];
#pragma unroll
        for (int r = 0; r < 16; ++r) p[r] = fexp2(scur[r]);
        uint4 f1 = make_uint4(cvt_pk_bf16(p[0],  p[1]),  cvt_pk_bf16(p[2],  p[3]),
                              cvt_pk_bf16(p[4],  p[5]),  cvt_pk_bf16(p[6],  p[7]));
        uint4 f2 = make_uint4(cvt_pk_bf16(p[8],  p[9]),  cvt_pk_bf16(p[10], p[11]),
                              cvt_pk_bf16(p[12], p[13]), cvt_pk_bf16(p[14], p[15]));
        const bfrag pf1 = __builtin_bit_cast(bfrag, f1);
        const bfrag pf2 = __builtin_bit_cast(bfrag, f2);
        oacc  = __builtin_amdgcn_mfma_f32_32x32x16_bf16(pf1, vA,    oacc,  0, 0, 0);
        oacc  = __builtin_amdgcn_mfma_f32_32x32x16_bf16(pf2, vB,    oacc,  0, 0, 0);
        lsacc = __builtin_amdgcn_mfma_f32_32x32x16_bf16(pf1, onesf, lsacc, 0, 0, 0);
        lsacc = __builtin_amdgcn_mfma_f32_32x32x16_bf16(pf2, onesf, lsacc, 0, 0, 0);
    }

    // normalize rows (reg r of oacc and lsacc both belong to row
    // q=(r&3)+8*(r>>2)+4h) and transpose O via the endgame LDS tile
#pragma unroll
    for (int r = 0; r < 16; ++r) {
        const int q = (r & 3) + 8 * (r >> 2) + 4 * h;
        tile[q * PSTR + l31] = (u16)f2bfs(oacc[r] / lsacc[r]);
    }

    asm volatile("" ::: "memory");   // endgame only: order tile write->read

    // O A-fragments: row=q=l31, k-slots d=8h+e
    bfrag oa0 = *reinterpret_cast<const bfrag*>(tile + l31 * PSTR + 8 * h);
    bfrag oa1 = *reinterpret_cast<const bfrag*>(tile + l31 * PSTR + 16 + 8 * h);

    // OUT[q][o] = O_norm @ Wp^T + bias: col=o=l31, row=q=(r&3)+8*(r>>2)+4h
    f32x16 oc;
#pragma unroll
    for (int r = 0; r < 16; ++r) oc[r] = bias;
    oc = __builtin_amdgcn_mfma_f32_32x32x16_bf16(oa0, wf0, oc, 0, 0, 0);
    oc = __builtin_amdgcn_mfma_f32_32x32x16_bf16(oa1, wf1, oc, 0, 0, 0);

    // store: reg group rr holds q = qbase + 8*rr + 4h + {0,1,2,3} at o=l31
    float* ob = out + (size_t)(bg * D + l31) * N + qbase + 4 * h;
#pragma unroll
    for (int rr = 0; rr < 4; ++rr)
        *reinterpret_cast<float4*>(ob + 8 * rr) =
            make_float4(oc[4 * rr], oc[4 * rr + 1], oc[4 * rr + 2], oc[4 * rr + 3]);
}

extern "C" void kernel_launch(void* const* d_in, const int* in_sizes, int n_in,
                              void* d_out, int out_size, void* d_ws, size_t ws_size,
                              hipStream_t stream) {
    const float* x  = (const float*)d_in[0];
    const float* Wq = (const float*)d_in[1];
    const float* bq = (const float*)d_in[2];
    const float* Wk = (const float*)d_in[3];
    const float* bk = (const float*)d_in[4];
    const float* Wv = (const float*)d_in[5];
    const float* bv = (const float*)d_in[6];
    const float* Wp = (const float*)d_in[7];
    const float* bp = (const float*)d_in[8];
    float* out = (float*)d_out;

    u16* Qb = (u16*)d_ws;                        // [16][4096][32] bf16 = 4 MB
    u16* K2 = Qb + (size_t)NBG * N * D;          // [16][4][4096][8] = 4 MB
    u16* V2 = K2 + (size_t)NBG * N * D;          // [16][256][2][32][8] = 4 MB

    proj_kernel<<<dim3(N / 256, NBG, 3), 256, 0, stream>>>(x, Wq, bq, Wk, bk, Wv, bv, Qb, K2, V2);
    attn_kernel<<<dim3(NBG * (N / 128)), 256, 0, stream>>>(Qb, K2, V2, Wp, bp, out);
}

// Round 17
// 70.097 us; speedup vs baseline: 1.2278x; 1.2278x over previous
//
#include <hip/hip_runtime.h>
#include <hip/hip_bf16.h>

// SelfAttention b=2, heads=8, D=32, n=4096 (64x64).
// Pass 1 (proj_kernel, z=Q/K/V): x -> Q bf16 [bg][n][32] (pre-scaled by
//   SCALE*log2e), K2 bf16 [bg][dgrp=d/8][key][8], V2 bf16 sigma-ordered
//   [bg][key16grp][h][d][8] (r15-proven: PV A-frags = direct cvt_pk of
//   exp2 outputs, no cross-lane ops).
// Pass 2 (attn_kernel): 32x32 MFMA flash attention, 32 q/wave.
//   r17: UNROLL x2 -- two independent tile chains (sA/sB) per iteration;
//   S[pair t+1] MFMAs + K/V prefetch (1 pair ahead) + two independent
//   exp2->cvt->PV chains give the scheduler 2x independent work to fill
//   the dependency gaps r16 exposed (both pipes <40% busy, 35% stall).
//   lsum on the matrix pipe via mfma(P,ones) (r15-proven, lane-local
//   normalize). Endgame LDS transpose for the Wp-projection (r13-proven).

constexpr int D = 32;
constexpr int N = 4096;
constexpr int NBG = 16;
constexpr float SCALE = 0.17677669529663687f;   // 32^-0.5
constexpr float LOG2E = 1.4426950408889634f;

using bfrag  = __attribute__((ext_vector_type(8))) short;   // 8 bf16
using s16x8  = __attribute__((ext_vector_type(8))) short;
using f32x16 = __attribute__((ext_vector_type(16))) float;
typedef unsigned short u16;
typedef unsigned int u32;

constexpr int PSTR = 34;            // endgame tile row stride in u16

__device__ __forceinline__ float fexp2(float x) { return __builtin_amdgcn_exp2f(x); }

__device__ __forceinline__ short f2bfs(float f) {
    __hip_bfloat16 h = __float2bfloat16(f);
    return (short)__builtin_bit_cast(u16, h);
}

__device__ __forceinline__ u32 cvt_pk_bf16(float lo, float hi) {
    u32 r;
    asm("v_cvt_pk_bf16_f32 %0, %1, %2" : "=v"(r) : "v"(lo), "v"(hi));
    return r;
}

// ---------------- pass 1: projections -> fragment-native bf16 scratch -----
__global__ __launch_bounds__(256) void proj_kernel(
    const float* __restrict__ x,
    const float* __restrict__ Wq, const float* __restrict__ bq,
    const float* __restrict__ Wk, const float* __restrict__ bk,
    const float* __restrict__ Wv, const float* __restrict__ bv,
    u16* __restrict__ Qb, u16* __restrict__ K2, u16* __restrict__ V2) {
    const int bg = blockIdx.y, g = bg & 7;
    const int z  = blockIdx.z;                       // 0=Q 1=K 2=V
    const int i  = blockIdx.x * 256 + threadIdx.x;   // key / pixel index

    const float* W  = (z == 0) ? Wq : (z == 1) ? Wk : Wv;
    const float* bb = (z == 0) ? bq : (z == 1) ? bk : bv;

    const float* xb = x + (size_t)bg * D * N;
    float xv[D];
#pragma unroll
    for (int d = 0; d < D; ++d) xv[d] = xb[(size_t)d * N + i];

    const float* w = W + g * D * D;
    float acc[D];
#pragma unroll
    for (int o = 0; o < D; ++o) {
        float a0 = 0.f, a1 = 0.f, a2 = 0.f, a3 = 0.f;
#pragma unroll
        for (int d = 0; d < D; d += 4) {
            a0 = fmaf(w[o * D + d    ], xv[d    ], a0);
            a1 = fmaf(w[o * D + d + 1], xv[d + 1], a1);
            a2 = fmaf(w[o * D + d + 2], xv[d + 2], a2);
            a3 = fmaf(w[o * D + d + 3], xv[d + 3], a3);
        }
        acc[o] = (a0 + a1) + (a2 + a3) + bb[g * D + o];
    }

    if (z == 0) {                                    // Q -> row [n][32]
        u16* dst = Qb + ((size_t)bg * N + i) * D;
#pragma unroll
        for (int t = 0; t < 4; ++t) {
            s16x8 v;
#pragma unroll
            for (int e = 0; e < 8; ++e) v[e] = f2bfs(acc[8 * t + e] * (SCALE * LOG2E));
            *reinterpret_cast<s16x8*>(dst + 8 * t) = v;
        }
    } else if (z == 1) {                             // K -> [dgrp][key][8]
        u16* kb2 = K2 + (size_t)bg * N * D;
#pragma unroll
        for (int t = 0; t < 4; ++t) {                // dgrp = t
            s16x8 v;
#pragma unroll
            for (int e = 0; e < 8; ++e) v[e] = f2bfs(acc[8 * t + e]);
            *reinterpret_cast<s16x8*>(kb2 + (size_t)t * N * 8 + (size_t)i * 8) = v;
        }
    } else {
        // V -> sigma-ordered [key16grp][h][d][8]:
        // key j=i&15 sits at h=(j>>2)&1, e=(j&3)+4*((j>>3)&1), matching the
        // S^T in-lane key order (row = (e&3)+8*(e>>2)+4h) -> no permswap.
        const int j  = i & 15;
        const int hh = (j >> 2) & 1;
        const int ee = (j & 3) + 4 * ((j >> 3) & 1);
        u16* vb2 = V2 + (size_t)bg * N * D + (size_t)(i >> 4) * 512 + hh * 256 + ee;
#pragma unroll
        for (int o = 0; o < D; ++o)
            vb2[o * 8] = (u16)f2bfs(acc[o]);
    }
}

// ---------------- pass 2: 32x32 MFMA flash attention, unroll x2 -----------
__global__ __launch_bounds__(256) void attn_kernel(
    const u16* __restrict__ Qb, const u16* __restrict__ K2, const u16* __restrict__ V2,
    const float* __restrict__ Wp, const float* __restrict__ bp,
    float* __restrict__ out) {
    const int s = blockIdx.x;
    const int bg = s & 15, qt = s >> 4, g = bg & 7;   // bg fastest -> XCD L2 reuse
    const int wid = threadIdx.x >> 6;
    const int lane = threadIdx.x & 63;
    const int l31 = lane & 31, h = lane >> 5;
    const int qbase = qt * 128 + wid * 32;            // 32 q rows per wave

    __shared__ u16 plds_all[4][32][PSTR];             // endgame transpose only
    u16* tile = &plds_all[wid][0][0];

    const u16* Qw = Qb + (size_t)bg * N * D;
    const u16* Kw = K2 + (size_t)bg * N * D;
    const u16* Vw = V2 + (size_t)bg * N * D;

    // Q B-fragments (col=q=l31, k-slots d=8h+e), held whole loop
    const u16* qrow = Qw + (size_t)(qbase + l31) * D + 8 * h;
    bfrag qf0 = *reinterpret_cast<const bfrag*>(qrow);
    bfrag qf1 = *reinterpret_cast<const bfrag*>(qrow + 16);

    // Wp B-fragments (col=o=l31, k-slots d=8h+e) + bias
    bfrag wf0, wf1;
    {
        const float* wrow = Wp + (size_t)(g * D + l31) * D + 8 * h;
#pragma unroll
        for (int e = 0; e < 8; ++e) { wf0[e] = f2bfs(wrow[e]); wf1[e] = f2bfs(wrow[16 + e]); }
    }
    const float bias = bp[g * D + l31];

    // ones B-fragment (bf16 1.0) for the lsum MFMA
    bfrag onesf;
#pragma unroll
    for (int e = 0; e < 8; ++e) onesf[e] = (short)0x3F80;

    const f32x16 zf16 = {};
    f32x16 oacc  = {};
    f32x16 lsacc = {};

    // fragment-native bases: every in-loop load is 1KB contiguous per wave
    const u16* kBase   = Kw + (size_t)h * N * 8 + (size_t)l31 * 8;  // dgrp h, key l31
    const u16* kHiBase = kBase + 2 * N * 8;                         // dgrp h+2
    const u16* vBase   = Vw + h * 256 + l31 * 8;                    // h-group, d=l31

    const int NT = N / 32;           // 128 tiles
    const int NP = NT / 2;           // 64 pairs

    // K/V tile addresses (u16 offsets): K tile tt -> tt*256; V tile tt -> tt*1024(+512)
    auto ldK  = [&](int tt, int hi) {
        return *reinterpret_cast<const bfrag*>((hi ? kHiBase : kBase) + (size_t)tt * 256);
    };
    auto ldV  = [&](int tt, int half) {
        return *reinterpret_cast<const bfrag*>(vBase + (size_t)tt * 1024 + half * 512);
    };

    // ---- prologue: S for tiles 0,1; K for tiles 2,3 ----
    bfrag kA0 = ldK(0, 0), kA1 = ldK(0, 1);
    bfrag kB0 = ldK(1, 0), kB1 = ldK(1, 1);
    bfrag vA0 = ldV(0, 0), vA1 = ldV(0, 1);
    bfrag vB0 = ldV(1, 0), vB1 = ldV(1, 1);

    f32x16 sA = __builtin_amdgcn_mfma_f32_32x32x16_bf16(kA0, qf0, zf16, 0, 0, 0);
    sA = __builtin_amdgcn_mfma_f32_32x32x16_bf16(kA1, qf1, sA, 0, 0, 0);
    f32x16 sB = __builtin_amdgcn_mfma_f32_32x32x16_bf16(kB0, qf0, zf16, 0, 0, 0);
    sB = __builtin_amdgcn_mfma_f32_32x32x16_bf16(kB1, qf1, sB, 0, 0, 0);

    kA0 = ldK(2, 0); kA1 = ldK(2, 1);
    kB0 = ldK(3, 0); kB1 = ldK(3, 1);

    for (int t = 0; t < NP - 1; ++t) {
        // S for pair t+1 (tiles 2t+2, 2t+3) -- independent of this pair's VALU
        f32x16 snA = __builtin_amdgcn_mfma_f32_32x32x16_bf16(kA0, qf0, zf16, 0, 0, 0);
        snA = __builtin_amdgcn_mfma_f32_32x32x16_bf16(kA1, qf1, snA, 0, 0, 0);
        f32x16 snB = __builtin_amdgcn_mfma_f32_32x32x16_bf16(kB0, qf0, zf16, 0, 0, 0);
        snB = __builtin_amdgcn_mfma_f32_32x32x16_bf16(kB1, qf1, snB, 0, 0, 0);

        // prefetch K for pair t+2 (clamped), V for pair t+1
        const int t4 = (2 * t + 4 < NT) ? (2 * t + 4) : (NT - 1);
        const int t5 = (2 * t + 5 < NT) ? (2 * t + 5) : (NT - 1);
        kA0 = ldK(t4, 0); kA1 = ldK(t4, 1);
        kB0 = ldK(t5, 0); kB1 = ldK(t5, 1);
        bfrag vnA0 = ldV(2 * t + 2, 0), vnA1 = ldV(2 * t + 2, 1);
        bfrag vnB0 = ldV(2 * t + 3, 0), vnB1 = ldV(2 * t + 3, 1);

        // chain A: exp2 -> pack -> PV (tile 2t)
        {
            float p[16];
#pragma unroll
            for (int r = 0; r < 16; ++r) p[r] = fexp2(sA[r]);
            uint4 f1 = make_uint4(cvt_pk_bf16(p[0],  p[1]),  cvt_pk_bf16(p[2],  p[3]),
                                  cvt_pk_bf16(p[4],  p[5]),  cvt_pk_bf16(p[6],  p[7]));
            uint4 f2 = make_uint4(cvt_pk_bf16(p[8],  p[9]),  cvt_pk_bf16(p[10], p[11]),
                                  cvt_pk_bf16(p[12], p[13]), cvt_pk_bf16(p[14], p[15]));
            const bfrag pf1 = __builtin_bit_cast(bfrag, f1);
            const bfrag pf2 = __builtin_bit_cast(bfrag, f2);
            oacc  = __builtin_amdgcn_mfma_f32_32x32x16_bf16(pf1, vA0,   oacc,  0, 0, 0);
            oacc  = __builtin_amdgcn_mfma_f32_32x32x16_bf16(pf2, vA1,   oacc,  0, 0, 0);
            lsacc = __builtin_amdgcn_mfma_f32_32x32x16_bf16(pf1, onesf, lsacc, 0, 0, 0);
            lsacc = __builtin_amdgcn_mfma_f32_32x32x16_bf16(pf2, onesf, lsacc, 0, 0, 0);
        }
        // chain B: exp2 -> pack -> PV (tile 2t+1)
        {
            float p[16];
#pragma unroll
            for (int r = 0; r < 16; ++r) p[r] = fexp2(sB[r]);
            uint4 f1 = make_uint4(cvt_pk_bf16(p[0],  p[1]),  cvt_pk_bf16(p[2],  p[3]),
                                  cvt_pk_bf16(p[4],  p[5]),  cvt_pk_bf16(p[6],  p[7]));
            uint4 f2 = make_uint4(cvt_pk_bf16(p[8],  p[9]),  cvt_pk_bf16(p[10], p[11]),
                                  cvt_pk_bf16(p[12], p[13]), cvt_pk_bf16(p[14], p[15]));
            const bfrag pf1 = __builtin_bit_cast(bfrag, f1);
            const bfrag pf2 = __builtin_bit_cast(bfrag, f2);
            oacc  = __builtin_amdgcn_mfma_f32_32x32x16_bf16(pf1, vB0,   oacc,  0, 0, 0);
            oacc  = __builtin_amdgcn_mfma_f32_32x32x16_bf16(pf2, vB1,   oacc,  0, 0, 0);
            lsacc = __builtin_amdgcn_mfma_f32_32x32x16_bf16(pf1, onesf, lsacc, 0, 0, 0);
            lsacc = __builtin_amdgcn_mfma_f32_32x32x16_bf16(pf2, onesf, lsacc, 0, 0, 0);
        }

        // rotate
        sA = snA; sB = snB;
        vA0 = vnA0; vA1 = vnA1; vB0 = vnB0; vB1 = vnB1;
    }

    // ---- epilogue: final pair (tiles NT-2, NT-1) ----
#pragma unroll
    for (int c = 0; c < 2; ++c) {
        const f32x16& sc = c ? sB : sA;
        float p[16];
#pragma unroll
        for (int r = 0; r < 16; ++r) p[r] = fexp2(sc[r]);
        uint4 f1 = make_uint4(cvt_pk_bf16(p[0],  p[1]),  cvt_pk_bf16(p[2],  p[3]),
                              cvt_pk_bf16(p[4],  p[5]),  cvt_pk_bf16(p[6],  p[7]));
        uint4 f2 = make_uint4(cvt_pk_bf16(p[8],  p[9]),  cvt_pk_bf16(p[10], p[11]),
                              cvt_pk_bf16(p[12], p[13]), cvt_pk_bf16(p[14], p[15]));
        const bfrag pf1 = __builtin_bit_cast(bfrag, f1);
        const bfrag pf2 = __builtin_bit_cast(bfrag, f2);
        oacc  = __builtin_amdgcn_mfma_f32_32x32x16_bf16(pf1, c ? vB0 : vA0, oacc,  0, 0, 0);
        oacc  = __builtin_amdgcn_mfma_f32_32x32x16_bf16(pf2, c ? vB1 : vA1, oacc,  0, 0, 0);
        lsacc = __builtin_amdgcn_mfma_f32_32x32x16_bf16(pf1, onesf, lsacc, 0, 0, 0);
        lsacc = __builtin_amdgcn_mfma_f32_32x32x16_bf16(pf2, onesf, lsacc, 0, 0, 0);
    }

    // normalize rows (reg r of oacc and lsacc both belong to row
    // q=(r&3)+8*(r>>2)+4h) and transpose O via the endgame LDS tile
#pragma unroll
    for (int r = 0; r < 16; ++r) {
        const int q = (r & 3) + 8 * (r >> 2) + 4 * h;
        tile[q * PSTR + l31] = (u16)f2bfs(oacc[r] / lsacc[r]);
    }

    asm volatile("" ::: "memory");   // endgame only: order tile write->read

    // O A-fragments: row=q=l31, k-slots d=8h+e
    bfrag oa0 = *reinterpret_cast<const bfrag*>(tile + l31 * PSTR + 8 * h);
    bfrag oa1 = *reinterpret_cast<const bfrag*>(tile + l31 * PSTR + 16 + 8 * h);

    // OUT[q][o] = O_norm @ Wp^T + bias: col=o=l31, row=q=(r&3)+8*(r>>2)+4h
    f32x16 oc;
#pragma unroll
    for (int r = 0; r < 16; ++r) oc[r] = bias;
    oc = __builtin_amdgcn_mfma_f32_32x32x16_bf16(oa0, wf0, oc, 0, 0, 0);
    oc = __builtin_amdgcn_mfma_f32_32x32x16_bf16(oa1, wf1, oc, 0, 0, 0);

    // store: reg group rr holds q = qbase + 8*rr + 4h + {0,1,2,3} at o=l31
    float* ob = out + (size_t)(bg * D + l31) * N + qbase + 4 * h;
#pragma unroll
    for (int rr = 0; rr < 4; ++rr)
        *reinterpret_cast<float4*>(ob + 8 * rr) =
            make_float4(oc[4 * rr], oc[4 * rr + 1], oc[4 * rr + 2], oc[4 * rr + 3]);
}

extern "C" void kernel_launch(void* const* d_in, const int* in_sizes, int n_in,
                              void* d_out, int out_size, void* d_ws, size_t ws_size,
                              hipStream_t stream) {
    const float* x  = (const float*)d_in[0];
    const float* Wq = (const float*)d_in[1];
    const float* bq = (const float*)d_in[2];
    const float* Wk = (const float*)d_in[3];
    const float* bk = (const float*)d_in[4];
    const float* Wv = (const float*)d_in[5];
    const float* bv = (const float*)d_in[6];
    const float* Wp = (const float*)d_in[7];
    const float* bp = (const float*)d_in[8];
    float* out = (float*)d_out;

    u16* Qb = (u16*)d_ws;                        // [16][4096][32] bf16 = 4 MB
    u16* K2 = Qb + (size_t)NBG * N * D;          // [16][4][4096][8] = 4 MB
    u16* V2 = K2 + (size_t)NBG * N * D;          // [16][256][2][32][8] = 4 MB

    proj_kernel<<<dim3(N / 256, NBG, 3), 256, 0, stream>>>(x, Wq, bq, Wk, bk, Wv, bv, Qb, K2, V2);
    attn_kernel<<<dim3(NBG * (N / 128)), 256, 0, stream>>>(Qb, K2, V2, Wp, bp, out);
}